// Round 12
// baseline (278.644 us; speedup 1.0000x reference)
//
#include <hip/hip_runtime.h>

typedef unsigned short ushort_t;
typedef __attribute__((ext_vector_type(8))) short s8v;    // 8 x bf16 (4 VGPRs)
typedef __attribute__((ext_vector_type(4))) float f4v;    // MFMA accumulator

#define NPT  4096
#define NC   128
#define NK   32
#define CIN  387
#define KPAD 416
#define WFR  136      // wf r-block stride (shorts)
#define WFP  680      // wf point stride = 5*WFR

__device__ __forceinline__ float bf2f(ushort_t u) {
    unsigned int x = ((unsigned int)u) << 16; float f; __builtin_memcpy(&f, &x, 4); return f;
}
__device__ __forceinline__ ushort_t f2bf(float f) {
    unsigned int x; __builtin_memcpy(&x, &f, 4);
    unsigned int r = x + 0x7fffu + ((x >> 16) & 1u);   // RNE
    return (ushort_t)(r >> 16);
}
__device__ __forceinline__ void splitbf(float x, ushort_t& h, ushort_t& l) {
    h = f2bf(x);
    l = f2bf(x - bf2f(h));
}

// ---------------------------------------------------------------- front: role-split single launch
// blocks [0,256): neighbor search, 64 pts/block (per-point math EXACT R8 body -> idxg bit-identical)
// blocks [256,1280): begin 1x1 conv + featT emit (direct wb reads; identical fmaf chains -> bit-identical)
// blocks [1280,1792): weight prep (EXACT R8 body, rebased; wbT dropped)
__global__ __launch_bounds__(256) void k_front(
    const float* pos, int* idxg,
    const float* feat, const float* wb, const float* bb,
    float* feat0, ushort_t* featT_hi, ushort_t* featT_lo,
    const float* qp, const float* kpw, const float* w1, const float* wend, const float* w2,
    float* out0,
    ushort_t* kpwT_hi, ushort_t* kpwT_lo, ushort_t* w1_hi, ushort_t* w1_lo,
    ushort_t* we_hi, ushort_t* we_lo, ushort_t* w2_hi, ushort_t* w2_lo)
{
    __shared__ float shp[3 * NPT];     // 49152 B; feat0 role uses first 8192 B
    int tid = threadIdx.x;
    if (blockIdx.x < 256) {
        // ---------- neighbor search, f64 distances (bit-matches np-f64 ref)
        float* px = shp; float* py = shp + NPT; float* pz = shp + 2 * NPT;
        int b = blockIdx.x >> 6;        // 64 blocks per batch
        int tile = blockIdx.x & 63;
        const float* pb = pos + (size_t)b * 3 * NPT;
        for (int i = tid; i < NPT; i += 256) {
            px[i] = pb[i];
            py[i] = pb[NPT + i];
            pz[i] = pb[2 * NPT + i];
        }
        __syncthreads();
        const double R2 = 0.2 * 0.2;
        int wave = tid >> 6, lane = tid & 63;
        unsigned long long below = (1ull << lane) - 1ull;
        for (int wp = 0; wp < 16; ++wp) {
            int n = tile * 64 + wave * 16 + wp;
            size_t bn = (size_t)b * NPT + n;
            double pnx = (double)px[n], pny = (double)py[n], pnz = (double)pz[n];
            double nn = pnx * pnx + pny * pny + pnz * pnz;
            int count = 0;
            for (int m0 = 0; m0 < NPT && count < NK; m0 += 64) {
                int m = m0 + lane;
                double qx = (double)px[m], qy = (double)py[m], qz = (double)pz[m];
                double nm = qx * qx + qy * qy + qz * qz;
                double dot = pnx * qx + pny * qy + pnz * qz;
                double sqd = (nn + nm) - 2.0 * dot;
                bool valid = !(sqd > R2);
                unsigned long long mask = __ballot(valid);
                int slot = count + __popcll(mask & below);
                if (valid && slot < NK) idxg[bn * NK + slot] = m;
                count += __popcll(mask);
            }
            int filled = count < NK ? count : NK;
            if (lane < NK && lane >= filled) idxg[bn * NK + lane] = -1;
        }
    } else if (blockIdx.x < 1280) {
        // ---------- begin 1x1 conv -> feat0 (f32) + featT hi/lo; 16 pts/block, 256 threads
        float* fl = shp;                 // [128][16] floats = 8192 B
        int fb = blockIdx.x - 256;
        int b = fb >> 8; int n0 = (fb & 255) * 16;
        for (int e = tid; e < 2048; e += 256) {
            int k = e >> 4, i = e & 15;
            fl[k * 16 + i] = feat[((size_t)b * NC + k) * NPT + n0 + i];
        }
        __syncthreads();
        for (int e = tid; e < 2048; e += 256) {
            int i = e >> 7, k = e & 127;
            ushort_t h, l;
            splitbf(fl[k * 16 + i], h, l);
            size_t o = ((size_t)b * NPT + n0 + i) * NC + k;
            featT_hi[o] = h; featT_lo[o] = l;
        }
        int ch = tid & 127;
        int ih = (tid >> 7) * 8;         // 0 or 8: which 8 points
        float acc[8];
        float bv = bb[ch];
        for (int j = 0; j < 8; ++j) acc[j] = bv;
        const float* wrow = wb + ch * NC;          // wb[ch][k] == wbT[k][ch]: same value, same fmaf order
        for (int k = 0; k < NC; ++k) {
            float w = wrow[k];
            for (int j = 0; j < 8; ++j) acc[j] = fmaf(w, fl[k * 16 + ih + j], acc[j]);
        }
        for (int j = 0; j < 8; ++j)
            feat0[((size_t)b * NPT + n0 + ih + j) * NC + ch] = acc[j];
    } else {
        // ---------- prep: out0 + weight hi/lo conversions (EXACT R8 body, rebased)
        int i = (blockIdx.x - 1280) * 256 + tid;
        int stride = 512 * 256;
        if (i < 12) { int c = i >> 2, r = (i & 3) + 1; out0[i] = qp[c * 5 + r]; }
        for (int e = i; e < 128 * WFP; e += stride) {
            int d = e / WFP, rem = e - d * WFP;
            int r = rem / WFR, c = rem - r * WFR;
            float v = (c < 128) ? kpw[(r * 128 + c) * 128 + d] : 0.0f;
            splitbf(v, kpwT_hi[e], kpwT_lo[e]);
        }
        for (int e = i; e < 256 * KPAD; e += stride) {
            int j = e / KPAD, cn = e - j * KPAD;
            float v = 0.0f;
            if (cn < 131)       v = w1[j * CIN + cn];
            else if (cn >= 160) v = w1[j * CIN + cn - 29];
            splitbf(v, w1_hi[e], w1_lo[e]);
        }
        for (int e = i; e < 128 * 128; e += stride) splitbf(wend[e], we_hi[e], we_lo[e]);
        for (int e = i; e < 128 * 256; e += stride) splitbf(w2[e],   w2_hi[e], w2_lo[e]);
    }
}

// ---------------------------------------------------------------- fused pipeline (EXACT R11 body)
__global__ __launch_bounds__(256, 3) void k_fused(
    const float* pos, const float* qp,
    const float* feat, const float* feat0, const int* idxg,
    const ushort_t* featT_hi, const ushort_t* featT_lo,
    const ushort_t* kpwT_hi, const ushort_t* kpwT_lo, const float* kp_bias,
    const ushort_t* we_hi, const ushort_t* we_lo, const float* b_end,
    const ushort_t* w1_hi, const ushort_t* w1_lo, const float* b1,
    const ushort_t* w2_hi, const ushort_t* w2_lo, const float* b2,
    float* outq)
{
    __shared__ __align__(16) char smem[53760];
    float*    wls   = (float*)smem;                  // [16][160] f32   (A,B)    0..10240
    ushort_t* q_hi  = (ushort_t*)smem;               // [16][136]       (C..E)   overlays wls
    ushort_t* q_lo  = (ushort_t*)(smem + 4352);
    ushort_t* wf_hi = (ushort_t*)(smem + 10240);     // [16][680]       (B..E)
    ushort_t* wf_lo = (ushort_t*)(smem + 32000);
    ushort_t* h_hi  = (ushort_t*)(smem + 10240);     // [64][136]       (F)      overlays wf
    ushort_t* h_lo  = (ushort_t*)(smem + 27648);
    float*    stg   = (float*)(smem + 10240);        // [128][65] f32   (F-epi)  overlays h

    const int tid = threadIdx.x;
    const int lane = tid & 63, wv = tid >> 6;
    const int l15 = lane & 15, quad = lane >> 4;
    const int p0 = blockIdx.x * 16;
    const int bL = p0 >> 12;
    const int nb = p0 & (NPT - 1);
    const int plq = l15 >> 2;
    const int rr  = (l15 & 3) + 1;

    // ---- phase A: recompute kernel-point weights (exact f32 replication) -> wls
    for (int e = tid; e < 512; e += 256) {
        int p = e >> 5, k = e & 31;
        int m = idxg[(size_t)p0 * NK + e];
        float w5[5];
        if (m < 0) {
            for (int r = 0; r < 5; ++r) w5[r] = 0.0f;
        } else {
            int n = nb + p;
            const float* pb = pos + (size_t)bL * 3 * NPT;
            float pnx = pb[n], pny = pb[NPT + n], pnz = pb[2 * NPT + n];
            float qx = pb[m], qy = pb[NPT + m], qz = pb[2 * NPT + m];
            float rx = __fsub_rn(qx, pnx), ry = __fsub_rn(qy, pny), rz = __fsub_rn(qz, pnz);
            for (int r = 0; r < 5; ++r) {
                float kx = qp[r], ky = qp[5 + r], kz = qp[10 + r];
                float dx = __fsub_rn(rx, kx), dy = __fsub_rn(ry, ky), dz = __fsub_rn(rz, kz);
                float s = __fadd_rn(__fadd_rn(__fmul_rn(dx, dx), __fmul_rn(dy, dy)), __fmul_rn(dz, dz));
                float w = 1.0f - __fdiv_rn(__fsqrt_rn(s), 0.1f);
                w5[r] = fmaxf(w, 0.0f);
            }
        }
        for (int r = 0; r < 5; ++r) wls[p * 160 + r * 32 + k] = w5[r];
    }
    __syncthreads();

    // ---- phase B: wf gather-reduce; idx via shfl broadcast; R6 scalar fmaf math (bit-identical)
    int idxA = idxg[(size_t)(p0 + wv * 4) * NK + lane];        // pts wv*4+0,1
    int idxB = idxg[(size_t)(p0 + wv * 4) * NK + 64 + lane];   // pts wv*4+2,3
    for (int pp = 0; pp < 4; ++pp) {
        int p = wv * 4 + pp;
        int src = (pp < 2) ? idxA : idxB;
        int blane = (pp & 1) * 32;
        float a0[5], a1[5];
        for (int r = 0; r < 5; ++r) { a0[r] = 0.f; a1[r] = 0.f; }
        for (int k = 0; k < NK; ++k) {
            int m = __shfl(src, blane + k);
            int mc = m < 0 ? 0 : m;
            const float* fp = feat0 + (((size_t)bL << 12) + mc) * NC + (lane << 1);
            float v0 = fp[0], v1 = fp[1];
            for (int r = 0; r < 5; ++r) {
                float w = wls[p * 160 + r * 32 + k];
                a0[r] = fmaf(w, v0, a0[r]);
                a1[r] = fmaf(w, v1, a1[r]);
            }
        }
        for (int r = 0; r < 5; ++r) {
            ushort_t h0, l0, h1, l1;
            splitbf(a0[r], h0, l0); splitbf(a1[r], h1, l1);
            int off = p * WFP + r * WFR + (lane << 1);
            *(unsigned int*)(wf_hi + off) = (unsigned int)h0 | ((unsigned int)h1 << 16);
            *(unsigned int*)(wf_lo + off) = (unsigned int)l0 | ((unsigned int)l1 << 16);
        }
    }
    __syncthreads();

    // ---- phase C: qf GEMM, term-split accumulators (6 independent MFMA chains)
    f4v ch[2], cm[2], cl[2];
    for (int nt = 0; nt < 2; ++nt) { ch[nt] = (f4v){0,0,0,0}; cm[nt] = (f4v){0,0,0,0}; cl[nt] = (f4v){0,0,0,0}; }
    for (int r = 0; r < 5; ++r)
        for (int kt = 0; kt < 4; ++kt) {
            int ao = l15 * WFP + r * WFR + kt * 32 + quad * 8;
            s8v ah = *(const s8v*)(wf_hi + ao);
            s8v al = *(const s8v*)(wf_lo + ao);
            for (int nt = 0; nt < 2; ++nt) {
                size_t ro = (size_t)(wv * 32 + nt * 16 + l15) * WFP + r * WFR + kt * 32 + quad * 8;
                s8v bh = *(const s8v*)(kpwT_hi + ro);
                s8v bl = *(const s8v*)(kpwT_lo + ro);
                ch[nt] = __builtin_amdgcn_mfma_f32_16x16x32_bf16(ah, bh, ch[nt], 0, 0, 0);
                cm[nt] = __builtin_amdgcn_mfma_f32_16x16x32_bf16(ah, bl, cm[nt], 0, 0, 0);
                cl[nt] = __builtin_amdgcn_mfma_f32_16x16x32_bf16(al, bh, cl[nt], 0, 0, 0);
            }
        }
    __syncthreads();                                 // load-bearing (R7/R9 regressions when removed)
    for (int nt = 0; nt < 2; ++nt) {
        int d = wv * 32 + nt * 16 + l15;
        float bias = kp_bias[d];
        f4v c1 = (ch[nt] + cm[nt]) + cl[nt];
        for (int reg = 0; reg < 4; ++reg) {
            int m = quad * 4 + reg;
            ushort_t vh, vl;
            splitbf(fmaxf(c1[reg] + bias, 0.0f), vh, vl);
            q_hi[m * 136 + d] = vh; q_lo[m * 136 + d] = vl;
        }
    }
    __syncthreads();

    // ---- phase D: w_end GEMM (term-split accs) + b_end + feat residual + relu -> q (in place)
    f4v dh[2], dm[2], dl[2];
    for (int nt = 0; nt < 2; ++nt) { dh[nt] = (f4v){0,0,0,0}; dm[nt] = (f4v){0,0,0,0}; dl[nt] = (f4v){0,0,0,0}; }
    for (int kt = 0; kt < 4; ++kt) {
        s8v ah = *(const s8v*)(q_hi + l15 * 136 + kt * 32 + quad * 8);
        s8v al = *(const s8v*)(q_lo + l15 * 136 + kt * 32 + quad * 8);
        for (int nt = 0; nt < 2; ++nt) {
            size_t ro = (size_t)(wv * 32 + nt * 16 + l15) * NC + kt * 32 + quad * 8;
            s8v bh = *(const s8v*)(we_hi + ro);
            s8v bl = *(const s8v*)(we_lo + ro);
            dh[nt] = __builtin_amdgcn_mfma_f32_16x16x32_bf16(ah, bh, dh[nt], 0, 0, 0);
            dm[nt] = __builtin_amdgcn_mfma_f32_16x16x32_bf16(ah, bl, dm[nt], 0, 0, 0);
            dl[nt] = __builtin_amdgcn_mfma_f32_16x16x32_bf16(al, bh, dl[nt], 0, 0, 0);
        }
    }
    __syncthreads();   // all q reads done before overwrite
    for (int nt = 0; nt < 2; ++nt) {
        int c = wv * 32 + nt * 16 + l15;
        float bias = b_end[c];
        f4v fv = *(const f4v*)(feat + ((size_t)(bL * NC + c)) * NPT + nb + quad * 4);
        f4v c2 = (dh[nt] + dm[nt]) + dl[nt];
        for (int reg = 0; reg < 4; ++reg) {
            int m = quad * 4 + reg;
            float v = c2[reg] + bias + fv[reg];
            ushort_t vh, vl;
            splitbf(fmaxf(v, 0.0f), vh, vl);
            q_hi[m * 136 + c] = vh; q_lo[m * 136 + c] = vl;
        }
    }
    __syncthreads();

    // ---- phase E: mlp1 (64 rows, K=416 reordered, N=256) -- zero staging, zero barriers
    union { s8v v; ushort_t u[8]; } aqp_h, aqp_l;
    for (int j = 0; j < 8; ++j) { aqp_h.u[j] = 0; aqp_l.u[j] = 0; }
    if (quad == 0)
        for (int j = 0; j < 3; ++j) splitbf(qp[j * 5 + rr], aqp_h.u[j], aqp_l.u[j]);

    f4v e1[4][4];
    for (int mt = 0; mt < 4; ++mt) for (int nt = 0; nt < 4; ++nt) e1[mt][nt] = (f4v){0,0,0,0};
    #pragma unroll
    for (int kt = 0; kt < 13; ++kt) {
        s8v ah[4], al[4];
        for (int mt = 0; mt < 4; ++mt) {
            int pl = mt * 4 + plq;
            if (kt < 4) {
                int ao = pl * WFP + rr * WFR + kt * 32 + quad * 8;
                ah[mt] = *(const s8v*)(wf_hi + ao);
                al[mt] = *(const s8v*)(wf_lo + ao);
            } else if (kt == 4) {
                ah[mt] = aqp_h.v; al[mt] = aqp_l.v;
            } else if (kt < 9) {
                int ao = pl * 136 + (kt - 5) * 32 + quad * 8;
                ah[mt] = *(const s8v*)(q_hi + ao);
                al[mt] = *(const s8v*)(q_lo + ao);
            } else {
                size_t go = (size_t)(p0 + pl) * NC + (kt - 9) * 32 + quad * 8;
                ah[mt] = *(const s8v*)(featT_hi + go);
                al[mt] = *(const s8v*)(featT_lo + go);
            }
        }
        for (int nt = 0; nt < 4; ++nt) {
            size_t ro = (size_t)(wv * 64 + nt * 16 + l15) * KPAD + kt * 32 + quad * 8;
            s8v bh = *(const s8v*)(w1_hi + ro);
            s8v bl = *(const s8v*)(w1_lo + ro);
            for (int mt = 0; mt < 4; ++mt) {
                e1[mt][nt] = __builtin_amdgcn_mfma_f32_16x16x32_bf16(ah[mt], bh, e1[mt][nt], 0, 0, 0);
                e1[mt][nt] = __builtin_amdgcn_mfma_f32_16x16x32_bf16(ah[mt], bl, e1[mt][nt], 0, 0, 0);
                e1[mt][nt] = __builtin_amdgcn_mfma_f32_16x16x32_bf16(al[mt], bh, e1[mt][nt], 0, 0, 0);
            }
        }
    }
    __syncthreads();                                 // all E reads done -> h overlays wf

    // ---- phase F: mlp2 in two K-halves; h staged hi/lo (R8 structure, all barriers)
    f4v f1[4][2];
    for (int mt = 0; mt < 4; ++mt) for (int nt = 0; nt < 2; ++nt) f1[mt][nt] = (f4v){0,0,0,0};
    for (int half = 0; half < 2; ++half) {
        if ((wv >> 1) == half) {
            for (int nt = 0; nt < 4; ++nt) {
                int j = wv * 64 + nt * 16 + l15;
                int col = j - half * 128;
                float bias = b1[j];
                for (int mt = 0; mt < 4; ++mt)
                    for (int reg = 0; reg < 4; ++reg) {
                        int m = mt * 16 + quad * 4 + reg;
                        ushort_t vh, vl;
                        splitbf(fmaxf(e1[mt][nt][reg] + bias, 0.0f), vh, vl);
                        h_hi[m * 136 + col] = vh; h_lo[m * 136 + col] = vl;
                    }
            }
        }
        __syncthreads();
        for (int kt = half * 4; kt < half * 4 + 4; ++kt) {
            int lcol = kt * 32 + quad * 8 - half * 128;
            s8v ah[4], al[4];
            for (int mt = 0; mt < 4; ++mt) {
                ah[mt] = *(const s8v*)(h_hi + (mt * 16 + l15) * 136 + lcol);
                al[mt] = *(const s8v*)(h_lo + (mt * 16 + l15) * 136 + lcol);
            }
            for (int nt = 0; nt < 2; ++nt) {
                size_t ro = (size_t)(wv * 32 + nt * 16 + l15) * 256 + kt * 32 + quad * 8;
                s8v bh = *(const s8v*)(w2_hi + ro);
                s8v bl = *(const s8v*)(w2_lo + ro);
                for (int mt = 0; mt < 4; ++mt) {
                    f1[mt][nt] = __builtin_amdgcn_mfma_f32_16x16x32_bf16(ah[mt], bh, f1[mt][nt], 0, 0, 0);
                    f1[mt][nt] = __builtin_amdgcn_mfma_f32_16x16x32_bf16(ah[mt], bl, f1[mt][nt], 0, 0, 0);
                    f1[mt][nt] = __builtin_amdgcn_mfma_f32_16x16x32_bf16(al[mt], bh, f1[mt][nt], 0, 0, 0);
                }
            }
        }
        __syncthreads();                             // last iter: fences h reads before stg overlay
    }

    // ---- F epilogue: LDS-stage [128 d][64 vals] (+1 pad) then coalesced 256B-run stores
    for (int nt = 0; nt < 2; ++nt) {
        int d = wv * 32 + nt * 16 + l15;
        float bias = b2[d];
        for (int mt = 0; mt < 4; ++mt) {
            int pt = mt * 4 + quad;
            for (int reg = 0; reg < 4; ++reg)
                stg[d * 65 + pt * 4 + reg] = fmaxf(f1[mt][nt][reg] + bias, 0.0f);
        }
    }
    __syncthreads();
    {
        float* obase = outq + (size_t)bL * 128 * NPT * 4 + (size_t)nb * 4;
        for (int it = 0; it < 32; ++it) {
            int idx = it * 256 + tid;
            int d = idx >> 6, off = idx & 63;
            obase[(size_t)d * (NPT * 4) + off] = stg[d * 65 + off];
        }
    }
}

extern "C" void kernel_launch(void* const* d_in, const int* in_sizes, int n_in,
                              void* d_out, int out_size, void* d_ws, size_t ws_size,
                              hipStream_t stream) {
    const float* pos     = (const float*)d_in[0];
    const float* feat    = (const float*)d_in[1];
    const float* qp      = (const float*)d_in[2];
    const float* w_begin = (const float*)d_in[3];
    const float* b_begin = (const float*)d_in[4];
    const float* kp_w    = (const float*)d_in[5];
    const float* kp_b    = (const float*)d_in[6];
    const float* w_end   = (const float*)d_in[7];
    const float* b_end   = (const float*)d_in[8];
    const float* w_mlp1  = (const float*)d_in[9];
    const float* b_mlp1  = (const float*)d_in[10];
    const float* w_mlp2  = (const float*)d_in[11];
    const float* b_mlp2  = (const float*)d_in[12];
    float* out = (float*)d_out;

    char* ws = (char*)d_ws;
    int*      idxg     = (int*)     (ws + 0);            //  2,097,152
    float*    feat0    = (float*)   (ws + 2097152);      //  8,388,608
    ushort_t* featT_hi = (ushort_t*)(ws + 10485760);     //  4,194,304
    ushort_t* featT_lo = (ushort_t*)(ws + 14680064);     //  4,194,304
    ushort_t* kpwT_hi  = (ushort_t*)(ws + 18874368);     //    174,080
    ushort_t* kpwT_lo  = (ushort_t*)(ws + 19048448);     //    174,080
    ushort_t* w1_hi    = (ushort_t*)(ws + 19222528);     //    212,992
    ushort_t* w1_lo    = (ushort_t*)(ws + 19435520);     //    212,992
    ushort_t* we_hi    = (ushort_t*)(ws + 19648512);     //     32,768
    ushort_t* we_lo    = (ushort_t*)(ws + 19681280);     //     32,768
    ushort_t* w2_hi    = (ushort_t*)(ws + 19714048);     //     65,536
    ushort_t* w2_lo    = (ushort_t*)(ws + 19779584);     //     65,536 (ends 19,845,120)

    k_front<<<1792, 256, 0, stream>>>(pos, idxg, feat, w_begin, b_begin,
                                      feat0, featT_hi, featT_lo,
                                      qp, kp_w, w_mlp1, w_end, w_mlp2, out,
                                      kpwT_hi, kpwT_lo, w1_hi, w1_lo, we_hi, we_lo,
                                      w2_hi, w2_lo);
    k_fused<<<1024, 256, 0, stream>>>(pos, qp, feat, feat0, idxg, featT_hi, featT_lo,
                                      kpwT_hi, kpwT_lo, kp_b, we_hi, we_lo, b_end,
                                      w1_hi, w1_lo, b_mlp1, w2_hi, w2_lo, b_mlp2, out + 12);
}

// Round 13
// 259.108 us; speedup vs baseline: 1.0754x; 1.0754x over previous
//
#include <hip/hip_runtime.h>

typedef unsigned short ushort_t;
typedef __attribute__((ext_vector_type(8))) short s8v;    // 8 x bf16 (4 VGPRs)
typedef __attribute__((ext_vector_type(4))) float f4v;    // MFMA accumulator

#define NPT  4096
#define NC   128
#define NK   32
#define CIN  387
#define KPAD 416
#define WFR  136      // wf r-block stride (shorts)
#define WFP  680      // wf point stride = 5*WFR

__device__ __forceinline__ float bf2f(ushort_t u) {
    unsigned int x = ((unsigned int)u) << 16; float f; __builtin_memcpy(&f, &x, 4); return f;
}
__device__ __forceinline__ ushort_t f2bf(float f) {
    unsigned int x; __builtin_memcpy(&x, &f, 4);
    unsigned int r = x + 0x7fffu + ((x >> 16) & 1u);   // RNE
    return (ushort_t)(r >> 16);
}
__device__ __forceinline__ void splitbf(float x, ushort_t& h, ushort_t& l) {
    h = f2bf(x);
    l = f2bf(x - bf2f(h));
}

// ---------------------------------------------------------------- front: role-split single launch
// blocks [0,1024): neighbor search (EXACT R8/R10 body/mapping -> idxg bit-identical)
// blocks [1024,2048): begin 1x1 conv + featT emit (direct wb reads; identical fmaf chains)
// blocks [2048,2560): weight prep (EXACT R8 body, rebased)
__global__ __launch_bounds__(256) void k_front(
    const float* pos, int* idxg,
    const float* feat, const float* wb, const float* bb,
    float* feat0, ushort_t* featT_hi, ushort_t* featT_lo,
    const float* qp, const float* kpw, const float* w1, const float* wend, const float* w2,
    float* out0,
    ushort_t* kpwT_hi, ushort_t* kpwT_lo, ushort_t* w1_hi, ushort_t* w1_lo,
    ushort_t* we_hi, ushort_t* we_lo, ushort_t* w2_hi, ushort_t* w2_lo)
{
    __shared__ float shp[3 * NPT];     // 49152 B; feat0 role uses first 8192 B
    int tid = threadIdx.x;
    if (blockIdx.x < 1024) {
        // ---------- neighbor search, f64 distances (bit-matches np-f64 ref; EXACT R8 body)
        float* px = shp; float* py = shp + NPT; float* pz = shp + 2 * NPT;
        int b = blockIdx.x >> 8;        // 256 blocks per batch
        int tile = blockIdx.x & 255;
        const float* pb = pos + (size_t)b * 3 * NPT;
        for (int i = tid; i < NPT; i += 256) {
            px[i] = pb[i];
            py[i] = pb[NPT + i];
            pz[i] = pb[2 * NPT + i];
        }
        __syncthreads();
        const double R2 = 0.2 * 0.2;
        int wave = tid >> 6, lane = tid & 63;
        unsigned long long below = (1ull << lane) - 1ull;
        for (int wp = 0; wp < 4; ++wp) {
            int n = tile * 16 + wave * 4 + wp;
            size_t bn = (size_t)b * NPT + n;
            double pnx = (double)px[n], pny = (double)py[n], pnz = (double)pz[n];
            double nn = pnx * pnx + pny * pny + pnz * pnz;
            int count = 0;
            for (int m0 = 0; m0 < NPT && count < NK; m0 += 64) {
                int m = m0 + lane;
                double qx = (double)px[m], qy = (double)py[m], qz = (double)pz[m];
                double nm = qx * qx + qy * qy + qz * qz;
                double dot = pnx * qx + pny * qy + pnz * qz;
                double sqd = (nn + nm) - 2.0 * dot;
                bool valid = !(sqd > R2);
                unsigned long long mask = __ballot(valid);
                int slot = count + __popcll(mask & below);
                if (valid && slot < NK) idxg[bn * NK + slot] = m;
                count += __popcll(mask);
            }
            int filled = count < NK ? count : NK;
            if (lane < NK && lane >= filled) idxg[bn * NK + lane] = -1;
        }
    } else if (blockIdx.x < 2048) {
        // ---------- begin 1x1 conv -> feat0 (f32) + featT hi/lo; 16 pts/block, 256 threads
        float* fl = shp;                 // [128][16] floats = 8192 B
        int fb = blockIdx.x - 1024;
        int b = fb >> 8; int n0 = (fb & 255) * 16;
        for (int e = tid; e < 2048; e += 256) {
            int k = e >> 4, i = e & 15;
            fl[k * 16 + i] = feat[((size_t)b * NC + k) * NPT + n0 + i];
        }
        __syncthreads();
        for (int e = tid; e < 2048; e += 256) {
            int i = e >> 7, k = e & 127;
            ushort_t h, l;
            splitbf(fl[k * 16 + i], h, l);
            size_t o = ((size_t)b * NPT + n0 + i) * NC + k;
            featT_hi[o] = h; featT_lo[o] = l;
        }
        int ch = tid & 127;
        int ih = (tid >> 7) * 8;         // 0 or 8: which 8 points
        float acc[8];
        float bv = bb[ch];
        for (int j = 0; j < 8; ++j) acc[j] = bv;
        const float* wrow = wb + ch * NC;          // wb[ch][k] == wbT[k][ch]: same value, same fmaf order
        for (int k = 0; k < NC; ++k) {
            float w = wrow[k];
            for (int j = 0; j < 8; ++j) acc[j] = fmaf(w, fl[k * 16 + ih + j], acc[j]);
        }
        for (int j = 0; j < 8; ++j)
            feat0[((size_t)b * NPT + n0 + ih + j) * NC + ch] = acc[j];
    } else {
        // ---------- prep: out0 + weight hi/lo conversions (EXACT R8 body, rebased)
        int i = (blockIdx.x - 2048) * 256 + tid;
        int stride = 512 * 256;
        if (i < 12) { int c = i >> 2, r = (i & 3) + 1; out0[i] = qp[c * 5 + r]; }
        for (int e = i; e < 128 * WFP; e += stride) {
            int d = e / WFP, rem = e - d * WFP;
            int r = rem / WFR, c = rem - r * WFR;
            float v = (c < 128) ? kpw[(r * 128 + c) * 128 + d] : 0.0f;
            splitbf(v, kpwT_hi[e], kpwT_lo[e]);
        }
        for (int e = i; e < 256 * KPAD; e += stride) {
            int j = e / KPAD, cn = e - j * KPAD;
            float v = 0.0f;
            if (cn < 131)       v = w1[j * CIN + cn];
            else if (cn >= 160) v = w1[j * CIN + cn - 29];
            splitbf(v, w1_hi[e], w1_lo[e]);
        }
        for (int e = i; e < 128 * 128; e += stride) splitbf(wend[e], we_hi[e], we_lo[e]);
        for (int e = i; e < 128 * 256; e += stride) splitbf(w2[e],   w2_hi[e], w2_lo[e]);
    }
}

// ---------------------------------------------------------------- fused pipeline (EXACT R11/R12 body)
__global__ __launch_bounds__(256, 3) void k_fused(
    const float* pos, const float* qp,
    const float* feat, const float* feat0, const int* idxg,
    const ushort_t* featT_hi, const ushort_t* featT_lo,
    const ushort_t* kpwT_hi, const ushort_t* kpwT_lo, const float* kp_bias,
    const ushort_t* we_hi, const ushort_t* we_lo, const float* b_end,
    const ushort_t* w1_hi, const ushort_t* w1_lo, const float* b1,
    const ushort_t* w2_hi, const ushort_t* w2_lo, const float* b2,
    float* outq)
{
    __shared__ __align__(16) char smem[53760];
    float*    wls   = (float*)smem;                  // [16][160] f32   (A,B)    0..10240
    ushort_t* q_hi  = (ushort_t*)smem;               // [16][136]       (C..E)   overlays wls
    ushort_t* q_lo  = (ushort_t*)(smem + 4352);
    ushort_t* wf_hi = (ushort_t*)(smem + 10240);     // [16][680]       (B..E)
    ushort_t* wf_lo = (ushort_t*)(smem + 32000);
    ushort_t* h_hi  = (ushort_t*)(smem + 10240);     // [64][136]       (F)      overlays wf
    ushort_t* h_lo  = (ushort_t*)(smem + 27648);
    float*    stg   = (float*)(smem + 10240);        // [128][65] f32   (F-epi)  overlays h

    const int tid = threadIdx.x;
    const int lane = tid & 63, wv = tid >> 6;
    const int l15 = lane & 15, quad = lane >> 4;
    const int p0 = blockIdx.x * 16;
    const int bL = p0 >> 12;
    const int nb = p0 & (NPT - 1);
    const int plq = l15 >> 2;
    const int rr  = (l15 & 3) + 1;

    // ---- phase A: recompute kernel-point weights (exact f32 replication) -> wls
    for (int e = tid; e < 512; e += 256) {
        int p = e >> 5, k = e & 31;
        int m = idxg[(size_t)p0 * NK + e];
        float w5[5];
        if (m < 0) {
            for (int r = 0; r < 5; ++r) w5[r] = 0.0f;
        } else {
            int n = nb + p;
            const float* pb = pos + (size_t)bL * 3 * NPT;
            float pnx = pb[n], pny = pb[NPT + n], pnz = pb[2 * NPT + n];
            float qx = pb[m], qy = pb[NPT + m], qz = pb[2 * NPT + m];
            float rx = __fsub_rn(qx, pnx), ry = __fsub_rn(qy, pny), rz = __fsub_rn(qz, pnz);
            for (int r = 0; r < 5; ++r) {
                float kx = qp[r], ky = qp[5 + r], kz = qp[10 + r];
                float dx = __fsub_rn(rx, kx), dy = __fsub_rn(ry, ky), dz = __fsub_rn(rz, kz);
                float s = __fadd_rn(__fadd_rn(__fmul_rn(dx, dx), __fmul_rn(dy, dy)), __fmul_rn(dz, dz));
                float w = 1.0f - __fdiv_rn(__fsqrt_rn(s), 0.1f);
                w5[r] = fmaxf(w, 0.0f);
            }
        }
        for (int r = 0; r < 5; ++r) wls[p * 160 + r * 32 + k] = w5[r];
    }
    __syncthreads();

    // ---- phase B: wf gather-reduce; idx via shfl broadcast; R6 scalar fmaf math (bit-identical)
    int idxA = idxg[(size_t)(p0 + wv * 4) * NK + lane];        // pts wv*4+0,1
    int idxB = idxg[(size_t)(p0 + wv * 4) * NK + 64 + lane];   // pts wv*4+2,3
    for (int pp = 0; pp < 4; ++pp) {
        int p = wv * 4 + pp;
        int src = (pp < 2) ? idxA : idxB;
        int blane = (pp & 1) * 32;
        float a0[5], a1[5];
        for (int r = 0; r < 5; ++r) { a0[r] = 0.f; a1[r] = 0.f; }
        for (int k = 0; k < NK; ++k) {
            int m = __shfl(src, blane + k);
            int mc = m < 0 ? 0 : m;
            const float* fp = feat0 + (((size_t)bL << 12) + mc) * NC + (lane << 1);
            float v0 = fp[0], v1 = fp[1];
            for (int r = 0; r < 5; ++r) {
                float w = wls[p * 160 + r * 32 + k];
                a0[r] = fmaf(w, v0, a0[r]);
                a1[r] = fmaf(w, v1, a1[r]);
            }
        }
        for (int r = 0; r < 5; ++r) {
            ushort_t h0, l0, h1, l1;
            splitbf(a0[r], h0, l0); splitbf(a1[r], h1, l1);
            int off = p * WFP + r * WFR + (lane << 1);
            *(unsigned int*)(wf_hi + off) = (unsigned int)h0 | ((unsigned int)h1 << 16);
            *(unsigned int*)(wf_lo + off) = (unsigned int)l0 | ((unsigned int)l1 << 16);
        }
    }
    __syncthreads();

    // ---- phase C: qf GEMM, term-split accumulators (6 independent MFMA chains)
    f4v ch[2], cm[2], cl[2];
    for (int nt = 0; nt < 2; ++nt) { ch[nt] = (f4v){0,0,0,0}; cm[nt] = (f4v){0,0,0,0}; cl[nt] = (f4v){0,0,0,0}; }
    for (int r = 0; r < 5; ++r)
        for (int kt = 0; kt < 4; ++kt) {
            int ao = l15 * WFP + r * WFR + kt * 32 + quad * 8;
            s8v ah = *(const s8v*)(wf_hi + ao);
            s8v al = *(const s8v*)(wf_lo + ao);
            for (int nt = 0; nt < 2; ++nt) {
                size_t ro = (size_t)(wv * 32 + nt * 16 + l15) * WFP + r * WFR + kt * 32 + quad * 8;
                s8v bh = *(const s8v*)(kpwT_hi + ro);
                s8v bl = *(const s8v*)(kpwT_lo + ro);
                ch[nt] = __builtin_amdgcn_mfma_f32_16x16x32_bf16(ah, bh, ch[nt], 0, 0, 0);
                cm[nt] = __builtin_amdgcn_mfma_f32_16x16x32_bf16(ah, bl, cm[nt], 0, 0, 0);
                cl[nt] = __builtin_amdgcn_mfma_f32_16x16x32_bf16(al, bh, cl[nt], 0, 0, 0);
            }
        }
    __syncthreads();                                 // load-bearing (R7/R9 regressions when removed)
    for (int nt = 0; nt < 2; ++nt) {
        int d = wv * 32 + nt * 16 + l15;
        float bias = kp_bias[d];
        f4v c1 = (ch[nt] + cm[nt]) + cl[nt];
        for (int reg = 0; reg < 4; ++reg) {
            int m = quad * 4 + reg;
            ushort_t vh, vl;
            splitbf(fmaxf(c1[reg] + bias, 0.0f), vh, vl);
            q_hi[m * 136 + d] = vh; q_lo[m * 136 + d] = vl;
        }
    }
    __syncthreads();

    // ---- phase D: w_end GEMM (term-split accs) + b_end + feat residual + relu -> q (in place)
    f4v dh[2], dm[2], dl[2];
    for (int nt = 0; nt < 2; ++nt) { dh[nt] = (f4v){0,0,0,0}; dm[nt] = (f4v){0,0,0,0}; dl[nt] = (f4v){0,0,0,0}; }
    for (int kt = 0; kt < 4; ++kt) {
        s8v ah = *(const s8v*)(q_hi + l15 * 136 + kt * 32 + quad * 8);
        s8v al = *(const s8v*)(q_lo + l15 * 136 + kt * 32 + quad * 8);
        for (int nt = 0; nt < 2; ++nt) {
            size_t ro = (size_t)(wv * 32 + nt * 16 + l15) * NC + kt * 32 + quad * 8;
            s8v bh = *(const s8v*)(we_hi + ro);
            s8v bl = *(const s8v*)(we_lo + ro);
            dh[nt] = __builtin_amdgcn_mfma_f32_16x16x32_bf16(ah, bh, dh[nt], 0, 0, 0);
            dm[nt] = __builtin_amdgcn_mfma_f32_16x16x32_bf16(ah, bl, dm[nt], 0, 0, 0);
            dl[nt] = __builtin_amdgcn_mfma_f32_16x16x32_bf16(al, bh, dl[nt], 0, 0, 0);
        }
    }
    __syncthreads();   // all q reads done before overwrite
    for (int nt = 0; nt < 2; ++nt) {
        int c = wv * 32 + nt * 16 + l15;
        float bias = b_end[c];
        f4v fv = *(const f4v*)(feat + ((size_t)(bL * NC + c)) * NPT + nb + quad * 4);
        f4v c2 = (dh[nt] + dm[nt]) + dl[nt];
        for (int reg = 0; reg < 4; ++reg) {
            int m = quad * 4 + reg;
            float v = c2[reg] + bias + fv[reg];
            ushort_t vh, vl;
            splitbf(fmaxf(v, 0.0f), vh, vl);
            q_hi[m * 136 + c] = vh; q_lo[m * 136 + c] = vl;
        }
    }
    __syncthreads();

    // ---- phase E: mlp1 (64 rows, K=416 reordered, N=256) -- zero staging, zero barriers
    union { s8v v; ushort_t u[8]; } aqp_h, aqp_l;
    for (int j = 0; j < 8; ++j) { aqp_h.u[j] = 0; aqp_l.u[j] = 0; }
    if (quad == 0)
        for (int j = 0; j < 3; ++j) splitbf(qp[j * 5 + rr], aqp_h.u[j], aqp_l.u[j]);

    f4v e1[4][4];
    for (int mt = 0; mt < 4; ++mt) for (int nt = 0; nt < 4; ++nt) e1[mt][nt] = (f4v){0,0,0,0};
    #pragma unroll
    for (int kt = 0; kt < 13; ++kt) {
        s8v ah[4], al[4];
        for (int mt = 0; mt < 4; ++mt) {
            int pl = mt * 4 + plq;
            if (kt < 4) {
                int ao = pl * WFP + rr * WFR + kt * 32 + quad * 8;
                ah[mt] = *(const s8v*)(wf_hi + ao);
                al[mt] = *(const s8v*)(wf_lo + ao);
            } else if (kt == 4) {
                ah[mt] = aqp_h.v; al[mt] = aqp_l.v;
            } else if (kt < 9) {
                int ao = pl * 136 + (kt - 5) * 32 + quad * 8;
                ah[mt] = *(const s8v*)(q_hi + ao);
                al[mt] = *(const s8v*)(q_lo + ao);
            } else {
                size_t go = (size_t)(p0 + pl) * NC + (kt - 9) * 32 + quad * 8;
                ah[mt] = *(const s8v*)(featT_hi + go);
                al[mt] = *(const s8v*)(featT_lo + go);
            }
        }
        for (int nt = 0; nt < 4; ++nt) {
            size_t ro = (size_t)(wv * 64 + nt * 16 + l15) * KPAD + kt * 32 + quad * 8;
            s8v bh = *(const s8v*)(w1_hi + ro);
            s8v bl = *(const s8v*)(w1_lo + ro);
            for (int mt = 0; mt < 4; ++mt) {
                e1[mt][nt] = __builtin_amdgcn_mfma_f32_16x16x32_bf16(ah[mt], bh, e1[mt][nt], 0, 0, 0);
                e1[mt][nt] = __builtin_amdgcn_mfma_f32_16x16x32_bf16(ah[mt], bl, e1[mt][nt], 0, 0, 0);
                e1[mt][nt] = __builtin_amdgcn_mfma_f32_16x16x32_bf16(al[mt], bh, e1[mt][nt], 0, 0, 0);
            }
        }
    }
    __syncthreads();                                 // all E reads done -> h overlays wf

    // ---- phase F: mlp2 in two K-halves; h staged hi/lo (R8 structure, all barriers)
    f4v f1[4][2];
    for (int mt = 0; mt < 4; ++mt) for (int nt = 0; nt < 2; ++nt) f1[mt][nt] = (f4v){0,0,0,0};
    for (int half = 0; half < 2; ++half) {
        if ((wv >> 1) == half) {
            for (int nt = 0; nt < 4; ++nt) {
                int j = wv * 64 + nt * 16 + l15;
                int col = j - half * 128;
                float bias = b1[j];
                for (int mt = 0; mt < 4; ++mt)
                    for (int reg = 0; reg < 4; ++reg) {
                        int m = mt * 16 + quad * 4 + reg;
                        ushort_t vh, vl;
                        splitbf(fmaxf(e1[mt][nt][reg] + bias, 0.0f), vh, vl);
                        h_hi[m * 136 + col] = vh; h_lo[m * 136 + col] = vl;
                    }
            }
        }
        __syncthreads();
        for (int kt = half * 4; kt < half * 4 + 4; ++kt) {
            int lcol = kt * 32 + quad * 8 - half * 128;
            s8v ah[4], al[4];
            for (int mt = 0; mt < 4; ++mt) {
                ah[mt] = *(const s8v*)(h_hi + (mt * 16 + l15) * 136 + lcol);
                al[mt] = *(const s8v*)(h_lo + (mt * 16 + l15) * 136 + lcol);
            }
            for (int nt = 0; nt < 2; ++nt) {
                size_t ro = (size_t)(wv * 32 + nt * 16 + l15) * 256 + kt * 32 + quad * 8;
                s8v bh = *(const s8v*)(w2_hi + ro);
                s8v bl = *(const s8v*)(w2_lo + ro);
                for (int mt = 0; mt < 4; ++mt) {
                    f1[mt][nt] = __builtin_amdgcn_mfma_f32_16x16x32_bf16(ah[mt], bh, f1[mt][nt], 0, 0, 0);
                    f1[mt][nt] = __builtin_amdgcn_mfma_f32_16x16x32_bf16(ah[mt], bl, f1[mt][nt], 0, 0, 0);
                    f1[mt][nt] = __builtin_amdgcn_mfma_f32_16x16x32_bf16(al[mt], bh, f1[mt][nt], 0, 0, 0);
                }
            }
        }
        __syncthreads();                             // last iter: fences h reads before stg overlay
    }

    // ---- F epilogue: LDS-stage [128 d][64 vals] (+1 pad) then coalesced 256B-run stores
    for (int nt = 0; nt < 2; ++nt) {
        int d = wv * 32 + nt * 16 + l15;
        float bias = b2[d];
        for (int mt = 0; mt < 4; ++mt) {
            int pt = mt * 4 + quad;
            for (int reg = 0; reg < 4; ++reg)
                stg[d * 65 + pt * 4 + reg] = fmaxf(f1[mt][nt][reg] + bias, 0.0f);
        }
    }
    __syncthreads();
    {
        float* obase = outq + (size_t)bL * 128 * NPT * 4 + (size_t)nb * 4;
        for (int it = 0; it < 32; ++it) {
            int idx = it * 256 + tid;
            int d = idx >> 6, off = idx & 63;
            obase[(size_t)d * (NPT * 4) + off] = stg[d * 65 + off];
        }
    }
}

extern "C" void kernel_launch(void* const* d_in, const int* in_sizes, int n_in,
                              void* d_out, int out_size, void* d_ws, size_t ws_size,
                              hipStream_t stream) {
    const float* pos     = (const float*)d_in[0];
    const float* feat    = (const float*)d_in[1];
    const float* qp      = (const float*)d_in[2];
    const float* w_begin = (const float*)d_in[3];
    const float* b_begin = (const float*)d_in[4];
    const float* kp_w    = (const float*)d_in[5];
    const float* kp_b    = (const float*)d_in[6];
    const float* w_end   = (const float*)d_in[7];
    const float* b_end   = (const float*)d_in[8];
    const float* w_mlp1  = (const float*)d_in[9];
    const float* b_mlp1  = (const float*)d_in[10];
    const float* w_mlp2  = (const float*)d_in[11];
    const float* b_mlp2  = (const float*)d_in[12];
    float* out = (float*)d_out;

    char* ws = (char*)d_ws;
    int*      idxg     = (int*)     (ws + 0);            //  2,097,152
    float*    feat0    = (float*)   (ws + 2097152);      //  8,388,608
    ushort_t* featT_hi = (ushort_t*)(ws + 10485760);     //  4,194,304
    ushort_t* featT_lo = (ushort_t*)(ws + 14680064);     //  4,194,304
    ushort_t* kpwT_hi  = (ushort_t*)(ws + 18874368);     //    174,080
    ushort_t* kpwT_lo  = (ushort_t*)(ws + 19048448);     //    174,080
    ushort_t* w1_hi    = (ushort_t*)(ws + 19222528);     //    212,992
    ushort_t* w1_lo    = (ushort_t*)(ws + 19435520);     //    212,992
    ushort_t* we_hi    = (ushort_t*)(ws + 19648512);     //     32,768
    ushort_t* we_lo    = (ushort_t*)(ws + 19681280);     //     32,768
    ushort_t* w2_hi    = (ushort_t*)(ws + 19714048);     //     65,536
    ushort_t* w2_lo    = (ushort_t*)(ws + 19779584);     //     65,536 (ends 19,845,120)

    k_front<<<2560, 256, 0, stream>>>(pos, idxg, feat, w_begin, b_begin,
                                      feat0, featT_hi, featT_lo,
                                      qp, kp_w, w_mlp1, w_end, w_mlp2, out,
                                      kpwT_hi, kpwT_lo, w1_hi, w1_lo, we_hi, we_lo,
                                      w2_hi, w2_lo);
    k_fused<<<1024, 256, 0, stream>>>(pos, qp, feat, feat0, idxg, featT_hi, featT_lo,
                                      kpwT_hi, kpwT_lo, kp_b, we_hi, we_lo, b_end,
                                      w1_hi, w1_lo, b_mlp1, w2_hi, w2_lo, b_mlp2, out + 12);
}